// Round 9
// baseline (583.504 us; speedup 1.0000x reference)
//
#include <hip/hip_runtime.h>
#include <hip/hip_bf16.h>
#include <hip/hip_fp16.h>
#include <math.h>

#define LEAK 0.2f
#define BSTRIDE 64  // bucket capacity per node; P(deg>64) ~ 1e-19

typedef _Float16 f16;
typedef _Float16 f16x2 __attribute__((ext_vector_type(2)));
typedef _Float16 f16x4 __attribute__((ext_vector_type(4)));
typedef _Float16 f16x8 __attribute__((ext_vector_type(8)));
typedef float f32x2 __attribute__((ext_vector_type(2)));
typedef float f32x4 __attribute__((ext_vector_type(4)));

__device__ inline unsigned char f32_to_fp8(float v) {
  int p = __builtin_amdgcn_cvt_pk_fp8_f32(v, v, 0, false);
  return (unsigned char)(p & 0xff);
}

// ---------------------------------------------------------------------------
// W[K][NC] fp32 -> Wt[NC][K] f16
// ---------------------------------------------------------------------------
__global__ void transpose_w_k(const float* __restrict__ W, f16* __restrict__ Wt,
                              int K, int NC) {
  int idx = blockIdx.x * 256 + threadIdx.x;
  if (idx >= K * NC) return;
  int n = idx / K, k = idx - n * K;
  Wt[idx] = (f16)W[(size_t)k * NC + n];
}

// ---------------------------------------------------------------------------
// MFMA GEMM + fused att logits + (optional) tail bucket-fill. See R8 notes:
// pad-free swizzled LDS (phys_chunk = (chunk+row)&(CH-1)), B pre-transposed.
// ---------------------------------------------------------------------------
template <int K, int DH, bool FP8OUT, bool FILL>
__global__ __launch_bounds__(256) void gemm_att_mfma_k(
    const float* __restrict__ A, const f16* __restrict__ Bt,
    void* __restrict__ Cout, const float* __restrict__ a_src,
    const float* __restrict__ a_dst, float* __restrict__ asrc,
    float* __restrict__ adst, int M, int NC,
    const int* __restrict__ ei, int E, int Nn,
    unsigned* __restrict__ cnt, unsigned* __restrict__ bucket) {
  constexpr int CH = K / 8;  // 16B chunks per row
  __shared__ f16 As[64 * K];
  __shared__ f16 Bs[64 * K];
  const int tid = threadIdx.x;
  const int row0 = blockIdx.y * 64;
  const int col0 = blockIdx.x * 64;

#pragma unroll
  for (int it = 0; it < (64 * CH) / 256; ++it) {
    int idx = it * 256 + tid;
    int r = idx / CH, c = idx - r * CH;
    int grow = row0 + r;
    float4 v0 = make_float4(0.f, 0.f, 0.f, 0.f), v1 = v0;
    if (grow < M) {
      const float* gp = A + (size_t)grow * K + c * 8;
      v0 = *(const float4*)gp;
      v1 = *(const float4*)(gp + 4);
    }
    f16x8 h = {(f16)v0.x, (f16)v0.y, (f16)v0.z, (f16)v0.w,
               (f16)v1.x, (f16)v1.y, (f16)v1.z, (f16)v1.w};
    *(f16x8*)&As[r * K + (((c + r) & (CH - 1)) << 3)] = h;
  }
#pragma unroll
  for (int it = 0; it < (64 * CH) / 256; ++it) {
    int idx = it * 256 + tid;
    int n = idx / CH, c = idx - n * CH;
    f16x8 h = *(const f16x8*)(Bt + (size_t)(col0 + n) * K + c * 8);
    *(f16x8*)&Bs[n * K + (((c + n) & (CH - 1)) << 3)] = h;
  }
  __syncthreads();

  const int wv = tid >> 6;
  const int lane = tid & 63;
  const int l16 = lane & 15;
  const int l4 = lane >> 4;

  f32x4 acc[4];
#pragma unroll
  for (int ct = 0; ct < 4; ++ct) acc[ct] = (f32x4){0.f, 0.f, 0.f, 0.f};

  const int ar = wv * 16 + l16;
#pragma unroll
  for (int kt = 0; kt < K / 32; ++kt) {
    int aj = kt * 4 + l4;
    f16x8 av = *(const f16x8*)&As[ar * K + (((aj + ar) & (CH - 1)) << 3)];
#pragma unroll
    for (int ct = 0; ct < 4; ++ct) {
      int br = ct * 16 + l16;
      f16x8 bv = *(const f16x8*)&Bs[br * K + (((aj + br) & (CH - 1)) << 3)];
      acc[ct] = __builtin_amdgcn_mfma_f32_16x16x32_f16(av, bv, acc[ct], 0, 0, 0);
    }
  }

  constexpr int HPB = 64 / DH;
  constexpr int CTH = DH / 16;
  float ps[HPB][4], pd[HPB][4];
#pragma unroll
  for (int hl = 0; hl < HPB; ++hl)
#pragma unroll
    for (int r = 0; r < 4; ++r) { ps[hl][r] = 0.f; pd[hl][r] = 0.f; }

#pragma unroll
  for (int ct = 0; ct < 4; ++ct) {
    int col = col0 + ct * 16 + l16;
    float vs = a_src[col];
    float vd = a_dst[col];
    int hl = ct / CTH;
#pragma unroll
    for (int r = 0; r < 4; ++r) {
      ps[hl][r] += acc[ct][r] * vs;
      pd[hl][r] += acc[ct][r] * vd;
      int grow = row0 + wv * 16 + l4 * 4 + r;
      if (grow < M) {
        if (FP8OUT) {
          ((unsigned char*)Cout)[(size_t)grow * NC + col] = f32_to_fp8(acc[ct][r]);
        } else {
          ((f16*)Cout)[(size_t)grow * NC + col] = (f16)acc[ct][r];
        }
      }
    }
  }

#pragma unroll
  for (int hl = 0; hl < HPB; ++hl) {
#pragma unroll
    for (int r = 0; r < 4; ++r) {
      float s = ps[hl][r], d = pd[hl][r];
#pragma unroll
      for (int m = 1; m < 16; m <<= 1) {
        s += __shfl_xor(s, m, 64);
        d += __shfl_xor(d, m, 64);
      }
      if (l16 == 0) {
        int grow = row0 + wv * 16 + l4 * 4 + r;
        int h = (col0 / DH) + hl;
        if (grow < M) {
          asrc[(size_t)grow * 8 + h] = s;
          adst[(size_t)grow * 8 + h] = d;
        }
      }
    }
  }

  if (FILL) {
    const int nthreads = (int)(gridDim.x * gridDim.y) * 256;
    const int Mtot = E + Nn;
    for (int p = (int)(blockIdx.y * gridDim.x + blockIdx.x) * 256 + tid;
         p < Mtot; p += nthreads) {
      int s, d;
      if (p < E) {
        s = ei[p];
        d = ei[E + p];
      } else {
        s = d = p - E;
      }
      unsigned pos = atomicAdd(&cnt[d], 1u);
      if (pos < BSTRIDE)
        __builtin_nontemporal_store((unsigned)s, &bucket[((size_t)d << 6) + pos]);
    }
  }
}

// ---------------------------------------------------------------------------
// Per-node normalized attention weights: one wave per dst node, lane = edge.
// Coalesced bucket read; 32B asrc gather + 8 exps per lane; butterfly
// normalize per head across lanes; 0.125 head-mean folded in. Stores compact
// f16x8 per edge slot (only deg slots touched -> ~27 MB traffic of the
// 102 MB allocation).
// ---------------------------------------------------------------------------
__global__ __launch_bounds__(256) void edge_w_k(const float* __restrict__ asrc,
                                                const float* __restrict__ adst,
                                                const unsigned* __restrict__ cnt,
                                                const unsigned* __restrict__ bucket,
                                                f16* __restrict__ w16, int N) {
  const int lane = threadIdx.x & 63;
  const int n = blockIdx.x * 4 + (threadIdx.x >> 6);
  if (n >= N) return;
  int deg = (int)cnt[n];
  deg = deg > BSTRIDE ? BSTRIDE : deg;
  unsigned s = bucket[((size_t)n << 6) + lane];

  float w[8];
  if (lane < deg) {
    const float4* ap = (const float4*)(asrc + (size_t)s * 8);
    const float4* bp = (const float4*)(adst + (size_t)n * 8);
    float4 a0 = ap[0], a1 = ap[1];
    float4 b0 = bp[0], b1 = bp[1];
    float e[8] = {a0.x + b0.x, a0.y + b0.y, a0.z + b0.z, a0.w + b0.w,
                  a1.x + b1.x, a1.y + b1.y, a1.z + b1.z, a1.w + b1.w};
#pragma unroll
    for (int j = 0; j < 8; ++j) {
      float t = e[j];
      t = t > 0.f ? t : LEAK * t;
      w[j] = __expf(t);
    }
  } else {
#pragma unroll
    for (int j = 0; j < 8; ++j) w[j] = 0.f;
  }

  // normalize per head (butterfly sum over the 64 lanes), fold 0.125
#pragma unroll
  for (int j = 0; j < 8; ++j) {
    float v = w[j];
#pragma unroll
    for (int m = 1; m < 64; m <<= 1) v += __shfl_xor(v, m, 64);
    w[j] = w[j] * (0.125f / v);
  }

  if (lane < deg) {
    f16x8 o = {(f16)w[0], (f16)w[1], (f16)w[2], (f16)w[3],
               (f16)w[4], (f16)w[5], (f16)w[6], (f16)w[7]};
    *(f16x8*)(w16 + ((((size_t)n << 6) + lane) << 3)) = o;
  }
}

// ---------------------------------------------------------------------------
// Layer-1 aggregation: one wave per dst node; weights pre-normalized (0.125
// folded). Messages fp8 e4m3: row 256 B -> 1 uint/lane; head h = lane>>3.
// Loop body: shfl src + 2B w broadcast + 4B row load + cvt + 4 fma.
// Epilogue: head-sum, + b1, ELU -> hout[n][32] fp32.
// ---------------------------------------------------------------------------
__global__ __launch_bounds__(256) void aggregate1_k(const unsigned char* __restrict__ xh8,
                                                    const f16* __restrict__ w16,
                                                    const unsigned* __restrict__ cnt,
                                                    const unsigned* __restrict__ bucket,
                                                    const float* __restrict__ b1,
                                                    float* __restrict__ hout, int N) {
  const int lane = threadIdx.x & 63;
  const int n = blockIdx.x * 4 + (threadIdx.x >> 6);
  if (n >= N) return;
  int deg = (int)cnt[n];
  deg = deg > BSTRIDE ? BSTRIDE : deg;
  const int h = lane >> 3;
  const unsigned sv = bucket[((size_t)n << 6) + lane];
  const unsigned int* xw = (const unsigned int*)xh8;  // row = 64 words
  const f16* wp = w16 + (((size_t)n << 6) << 3) + h;

  float acc0 = 0.f, acc1 = 0.f, acc2 = 0.f, acc3 = 0.f;
#pragma unroll 4
  for (int i = 0; i < deg; ++i) {
    unsigned s = __shfl(sv, i, 64);
    float w = (float)wp[i * 8];
    unsigned int b = xw[(size_t)s * 64 + lane];
    f32x2 lo = __builtin_amdgcn_cvt_pk_f32_fp8(b, false);
    f32x2 hi = __builtin_amdgcn_cvt_pk_f32_fp8(b, true);
    acc0 += w * lo.x;
    acc1 += w * lo.y;
    acc2 += w * hi.x;
    acc3 += w * hi.y;
  }

  // sum over heads: lanes with equal (lane & 7)
#pragma unroll
  for (int m = 8; m < 64; m <<= 1) {
    acc0 += __shfl_xor(acc0, m, 64);
    acc1 += __shfl_xor(acc1, m, 64);
    acc2 += __shfl_xor(acc2, m, 64);
    acc3 += __shfl_xor(acc3, m, 64);
  }
  if (lane < 8) {
    int d = lane * 4;
    float4 bv = *(const float4*)(b1 + d);
    float o0 = acc0 + bv.x;
    float o1 = acc1 + bv.y;
    float o2 = acc2 + bv.z;
    float o3 = acc3 + bv.w;
    o0 = o0 > 0.f ? o0 : expm1f(o0);
    o1 = o1 > 0.f ? o1 : expm1f(o1);
    o2 = o2 > 0.f ? o2 : expm1f(o2);
    o3 = o3 > 0.f ? o3 : expm1f(o3);
    *(float4*)(hout + (size_t)n * 32 + d) = make_float4(o0, o1, o2, o3);
  }
}

// ---------------------------------------------------------------------------
// Layer-2 aggregation + log_softmax. Messages fp8: row 128 B -> 2B/lane
// (cols (lane&7)*2+{0,1} of head lane>>3). Pre-normalized weights.
// out[0:N*16] = log_softmax, out[N*16:] = logits.
// ---------------------------------------------------------------------------
__global__ __launch_bounds__(256) void aggregate2_k(const unsigned char* __restrict__ xq,
                                                    const f16* __restrict__ w16,
                                                    const unsigned* __restrict__ cnt,
                                                    const unsigned* __restrict__ bucket,
                                                    const float* __restrict__ b2,
                                                    float* __restrict__ out, int N) {
  const int lane = threadIdx.x & 63;
  const int n = blockIdx.x * 4 + (threadIdx.x >> 6);
  if (n >= N) return;
  int deg = (int)cnt[n];
  deg = deg > BSTRIDE ? BSTRIDE : deg;
  const int h = lane >> 3;
  const unsigned sv = bucket[((size_t)n << 6) + lane];
  const f16* wp = w16 + (((size_t)n << 6) << 3) + h;

  float acc0 = 0.f, acc1 = 0.f;
#pragma unroll 4
  for (int i = 0; i < deg; ++i) {
    unsigned s = __shfl(sv, i, 64);
    float w = (float)wp[i * 8];
    unsigned short raw = *(const unsigned short*)(xq + (size_t)s * 128 + lane * 2);
    f32x2 v = __builtin_amdgcn_cvt_pk_f32_fp8((int)raw, false);
    acc0 += w * v.x;
    acc1 += w * v.y;
  }

#pragma unroll
  for (int m = 8; m < 64; m <<= 1) {
    acc0 += __shfl_xor(acc0, m, 64);
    acc1 += __shfl_xor(acc1, m, 64);
  }
  int c = (lane & 7) * 2;
  float l0 = acc0 + b2[c];
  float l1 = acc1 + b2[c + 1];

  float m2 = fmaxf(l0, l1);
#pragma unroll
  for (int m = 1; m < 8; m <<= 1) m2 = fmaxf(m2, __shfl_xor(m2, m, 64));
  float es = __expf(l0 - m2) + __expf(l1 - m2);
#pragma unroll
  for (int m = 1; m < 8; m <<= 1) es += __shfl_xor(es, m, 64);
  float lse = logf(es) + m2;

  if (lane < 8) {
    *(float2*)(out + (size_t)n * 16 + c) = make_float2(l0 - lse, l1 - lse);
    *(float2*)(out + (size_t)N * 16 + (size_t)n * 16 + c) = make_float2(l0, l1);
  }
}

// ---------------------------------------------------------------------------
extern "C" void kernel_launch(void* const* d_in, const int* in_sizes, int n_in,
                              void* d_out, int out_size, void* d_ws, size_t ws_size,
                              hipStream_t stream) {
  const float* x      = (const float*)d_in[0];
  const int*   ei     = (const int*)d_in[1];
  const float* W1     = (const float*)d_in[2];
  const float* a_src1 = (const float*)d_in[3];
  const float* a_dst1 = (const float*)d_in[4];
  const float* b1     = (const float*)d_in[5];
  const float* W2     = (const float*)d_in[6];
  const float* a_src2 = (const float*)d_in[7];
  const float* a_dst2 = (const float*)d_in[8];
  const float* b2     = (const float*)d_in[9];

  const int N = in_sizes[0] / 128;  // F = 128
  const int E = in_sizes[1] / 2;

  char* w = (char*)d_ws;
  size_t used = 0;
  auto alloc = [&](size_t bytes) -> void* {
    size_t aligned = (bytes + 255) & ~(size_t)255;
    void* p = w + used;
    used += aligned;
    return p;
  };
  unsigned char* xh1q = (unsigned char*)alloc((size_t)N * 256);  // fp8 L1 rows
  unsigned char* xh2q = xh1q;  // alias: gemm2 writes after agg1 consumed xh1q
  float*    hbuf   = (float*)alloc((size_t)N * 32 * 4);
  float*    asrc   = (float*)alloc((size_t)N * 8 * 4);   // reused L1 then L2
  float*    adst   = (float*)alloc((size_t)N * 8 * 4);
  unsigned* cnt    = (unsigned*)alloc((size_t)N * 4);
  unsigned* bucket = (unsigned*)alloc((size_t)N * BSTRIDE * 4);
  f16*      w16    = (f16*)alloc((size_t)N * BSTRIDE * 8 * 2);  // 102.4 MB, sparse-touched
  f16*      w1t    = (f16*)alloc((size_t)128 * 256 * 2);
  f16*      w2t    = (f16*)alloc((size_t)32 * 128 * 2);
  (void)ws_size;

  float* out = (float*)d_out;
  const int gy = (N + 63) / 64;

  // ---- prep ----
  transpose_w_k<<<(128 * 256 + 255) / 256, 256, 0, stream>>>(W1, w1t, 128, 256);
  transpose_w_k<<<(32 * 128 + 255) / 256, 256, 0, stream>>>(W2, w2t, 32, 128);
  hipMemsetAsync(cnt, 0, (size_t)N * 4, stream);

  // ---- Layer 1: MFMA GEMM + att logits + fp8 store + tail bucket-fill ----
  gemm_att_mfma_k<128, 32, true, true><<<dim3(4, gy), 256, 0, stream>>>(
      x, w1t, xh1q, a_src1, a_dst1, asrc, adst, N, 256, ei, E, N, cnt, bucket);

  // ---- Layer 1 weights + aggregation -> h ----
  edge_w_k<<<(N + 3) / 4, 256, 0, stream>>>(asrc, adst, cnt, bucket, w16, N);
  aggregate1_k<<<(N + 3) / 4, 256, 0, stream>>>(xh1q, w16, cnt, bucket, b1, hbuf, N);

  // ---- Layer 2 ----
  gemm_att_mfma_k<32, 16, true, false><<<dim3(2, gy), 256, 0, stream>>>(
      hbuf, w2t, xh2q, a_src2, a_dst2, asrc, adst, N, 128, nullptr, 0, 0, nullptr, nullptr);
  edge_w_k<<<(N + 3) / 4, 256, 0, stream>>>(asrc, adst, cnt, bucket, w16, N);
  aggregate2_k<<<(N + 3) / 4, 256, 0, stream>>>(xh2q, w16, cnt, bucket, b2, out, N);
}

// Round 10
// 516.198 us; speedup vs baseline: 1.1304x; 1.1304x over previous
//
#include <hip/hip_runtime.h>
#include <hip/hip_bf16.h>
#include <hip/hip_fp16.h>
#include <math.h>

#define LEAK 0.2f
#define BSTRIDE 64  // bucket capacity per node; P(deg>64) ~ 1e-19

typedef _Float16 f16;
typedef _Float16 f16x2 __attribute__((ext_vector_type(2)));
typedef _Float16 f16x4 __attribute__((ext_vector_type(4)));
typedef _Float16 f16x8 __attribute__((ext_vector_type(8)));
typedef float f32x2 __attribute__((ext_vector_type(2)));
typedef float f32x4 __attribute__((ext_vector_type(4)));

__device__ inline unsigned char f32_to_fp8(float v) {
  int p = __builtin_amdgcn_cvt_pk_fp8_f32(v, v, 0, false);
  return (unsigned char)(p & 0xff);
}

// ---------------------------------------------------------------------------
// W[K][NC] fp32 -> Wt[NC][K] f16
// ---------------------------------------------------------------------------
__global__ void transpose_w_k(const float* __restrict__ W, f16* __restrict__ Wt,
                              int K, int NC) {
  int idx = blockIdx.x * 256 + threadIdx.x;
  if (idx >= K * NC) return;
  int n = idx / K, k = idx - n * K;
  Wt[idx] = (f16)W[(size_t)k * NC + n];
}

// ---------------------------------------------------------------------------
// MFMA GEMM + fused att logits + (optional) tail bucket-fill.
// Pad-free swizzled LDS (phys_chunk = (chunk+row)&(CH-1)); B pre-transposed.
// Fill tail: plain cnt + nontemporal bucket stores (R9-measured faster than
// padded counters).
// ---------------------------------------------------------------------------
template <int K, int DH, bool FP8OUT, bool FILL>
__global__ __launch_bounds__(256) void gemm_att_mfma_k(
    const float* __restrict__ A, const f16* __restrict__ Bt,
    void* __restrict__ Cout, const float* __restrict__ a_src,
    const float* __restrict__ a_dst, float* __restrict__ asrc,
    float* __restrict__ adst, int M, int NC,
    const int* __restrict__ ei, int E, int Nn,
    unsigned* __restrict__ cnt, unsigned* __restrict__ bucket) {
  constexpr int CH = K / 8;  // 16B chunks per row
  __shared__ f16 As[64 * K];
  __shared__ f16 Bs[64 * K];
  const int tid = threadIdx.x;
  const int row0 = blockIdx.y * 64;
  const int col0 = blockIdx.x * 64;

#pragma unroll
  for (int it = 0; it < (64 * CH) / 256; ++it) {
    int idx = it * 256 + tid;
    int r = idx / CH, c = idx - r * CH;
    int grow = row0 + r;
    float4 v0 = make_float4(0.f, 0.f, 0.f, 0.f), v1 = v0;
    if (grow < M) {
      const float* gp = A + (size_t)grow * K + c * 8;
      v0 = *(const float4*)gp;
      v1 = *(const float4*)(gp + 4);
    }
    f16x8 h = {(f16)v0.x, (f16)v0.y, (f16)v0.z, (f16)v0.w,
               (f16)v1.x, (f16)v1.y, (f16)v1.z, (f16)v1.w};
    *(f16x8*)&As[r * K + (((c + r) & (CH - 1)) << 3)] = h;
  }
#pragma unroll
  for (int it = 0; it < (64 * CH) / 256; ++it) {
    int idx = it * 256 + tid;
    int n = idx / CH, c = idx - n * CH;
    f16x8 h = *(const f16x8*)(Bt + (size_t)(col0 + n) * K + c * 8);
    *(f16x8*)&Bs[n * K + (((c + n) & (CH - 1)) << 3)] = h;
  }
  __syncthreads();

  const int wv = tid >> 6;
  const int lane = tid & 63;
  const int l16 = lane & 15;
  const int l4 = lane >> 4;

  f32x4 acc[4];
#pragma unroll
  for (int ct = 0; ct < 4; ++ct) acc[ct] = (f32x4){0.f, 0.f, 0.f, 0.f};

  const int ar = wv * 16 + l16;
#pragma unroll
  for (int kt = 0; kt < K / 32; ++kt) {
    int aj = kt * 4 + l4;
    f16x8 av = *(const f16x8*)&As[ar * K + (((aj + ar) & (CH - 1)) << 3)];
#pragma unroll
    for (int ct = 0; ct < 4; ++ct) {
      int br = ct * 16 + l16;
      f16x8 bv = *(const f16x8*)&Bs[br * K + (((aj + br) & (CH - 1)) << 3)];
      acc[ct] = __builtin_amdgcn_mfma_f32_16x16x32_f16(av, bv, acc[ct], 0, 0, 0);
    }
  }

  constexpr int HPB = 64 / DH;
  constexpr int CTH = DH / 16;
  float ps[HPB][4], pd[HPB][4];
#pragma unroll
  for (int hl = 0; hl < HPB; ++hl)
#pragma unroll
    for (int r = 0; r < 4; ++r) { ps[hl][r] = 0.f; pd[hl][r] = 0.f; }

#pragma unroll
  for (int ct = 0; ct < 4; ++ct) {
    int col = col0 + ct * 16 + l16;
    float vs = a_src[col];
    float vd = a_dst[col];
    int hl = ct / CTH;
#pragma unroll
    for (int r = 0; r < 4; ++r) {
      ps[hl][r] += acc[ct][r] * vs;
      pd[hl][r] += acc[ct][r] * vd;
      int grow = row0 + wv * 16 + l4 * 4 + r;
      if (grow < M) {
        if (FP8OUT) {
          ((unsigned char*)Cout)[(size_t)grow * NC + col] = f32_to_fp8(acc[ct][r]);
        } else {
          ((f16*)Cout)[(size_t)grow * NC + col] = (f16)acc[ct][r];
        }
      }
    }
  }

#pragma unroll
  for (int hl = 0; hl < HPB; ++hl) {
#pragma unroll
    for (int r = 0; r < 4; ++r) {
      float s = ps[hl][r], d = pd[hl][r];
#pragma unroll
      for (int m = 1; m < 16; m <<= 1) {
        s += __shfl_xor(s, m, 64);
        d += __shfl_xor(d, m, 64);
      }
      if (l16 == 0) {
        int grow = row0 + wv * 16 + l4 * 4 + r;
        int h = (col0 / DH) + hl;
        if (grow < M) {
          asrc[(size_t)grow * 8 + h] = s;
          adst[(size_t)grow * 8 + h] = d;
        }
      }
    }
  }

  if (FILL) {
    const int nthreads = (int)(gridDim.x * gridDim.y) * 256;
    const int Mtot = E + Nn;
    for (int p = (int)(blockIdx.y * gridDim.x + blockIdx.x) * 256 + tid;
         p < Mtot; p += nthreads) {
      int s, d;
      if (p < E) {
        s = ei[p];
        d = ei[E + p];
      } else {
        s = d = p - E;
      }
      unsigned pos = atomicAdd(&cnt[d], 1u);
      if (pos < BSTRIDE)
        __builtin_nontemporal_store((unsigned)s, &bucket[((size_t)d << 6) + pos]);
    }
  }
}

// ---------------------------------------------------------------------------
// Layer-1 aggregation, two-phase per wave:
//  Phase A (lane = edge): coalesced bucket read; gather asrc[s] (32B/lane),
//    compute 8 head weights, butterfly-normalize (denominator + 0.125 head
//    mean folded), store fp32 w to LDS [wave][edge][head].
//  Phase B (lane = head/dim): loop edges: shfl src + conflict-free LDS w
//    broadcast + 4B fp8 row load + cvt + 4 fma. Epilogue: head-sum + b1 +
//    ELU -> hout[n][32].
// ---------------------------------------------------------------------------
__global__ __launch_bounds__(256) void aggregate1_k(const unsigned char* __restrict__ xh8,
                                                    const float* __restrict__ asrc,
                                                    const float* __restrict__ adst,
                                                    const unsigned* __restrict__ cnt,
                                                    const unsigned* __restrict__ bucket,
                                                    const float* __restrict__ b1,
                                                    float* __restrict__ hout, int N) {
  __shared__ float wlds[4][64][8];
  const int lane = threadIdx.x & 63;
  const int wv = threadIdx.x >> 6;
  const int n = blockIdx.x * 4 + wv;
  const int nn = n < N ? n : N - 1;  // clamp so no wave skips the barrier
  int deg = (int)cnt[nn];
  deg = deg > BSTRIDE ? BSTRIDE : deg;
  const unsigned sv = bucket[((size_t)nn << 6) + lane];

  // ---- Phase A: per-edge weights, all edges in parallel ----
  float w[8];
  if (lane < deg) {
    const float4* ap = (const float4*)(asrc + (size_t)sv * 8);
    const float4* bp = (const float4*)(adst + (size_t)nn * 8);
    float4 a0 = ap[0], a1 = ap[1];
    float4 b0 = bp[0], b1v = bp[1];
    float e[8] = {a0.x + b0.x, a0.y + b0.y, a0.z + b0.z, a0.w + b0.w,
                  a1.x + b1v.x, a1.y + b1v.y, a1.z + b1v.z, a1.w + b1v.w};
#pragma unroll
    for (int j = 0; j < 8; ++j) {
      float t = e[j];
      t = t > 0.f ? t : LEAK * t;
      w[j] = __expf(t);
    }
  } else {
#pragma unroll
    for (int j = 0; j < 8; ++j) w[j] = 0.f;
  }
#pragma unroll
  for (int j = 0; j < 8; ++j) {
    float v = w[j];
#pragma unroll
    for (int m = 1; m < 64; m <<= 1) v += __shfl_xor(v, m, 64);
    wlds[wv][lane][j] = w[j] * (0.125f / v);
  }
  __syncthreads();
  if (n >= N) return;

  // ---- Phase B: weighted row accumulate ----
  const int h = lane >> 3;
  const unsigned int* xw = (const unsigned int*)xh8;  // row = 64 words
  const float* wp = &wlds[wv][0][h];

  float acc0 = 0.f, acc1 = 0.f, acc2 = 0.f, acc3 = 0.f;
#pragma unroll 4
  for (int i = 0; i < deg; ++i) {
    unsigned s = __shfl(sv, i, 64);
    float w8 = wp[i * 8];
    unsigned int b = xw[(size_t)s * 64 + lane];
    f32x2 lo = __builtin_amdgcn_cvt_pk_f32_fp8(b, false);
    f32x2 hi = __builtin_amdgcn_cvt_pk_f32_fp8(b, true);
    acc0 += w8 * lo.x;
    acc1 += w8 * lo.y;
    acc2 += w8 * hi.x;
    acc3 += w8 * hi.y;
  }

#pragma unroll
  for (int m = 8; m < 64; m <<= 1) {
    acc0 += __shfl_xor(acc0, m, 64);
    acc1 += __shfl_xor(acc1, m, 64);
    acc2 += __shfl_xor(acc2, m, 64);
    acc3 += __shfl_xor(acc3, m, 64);
  }
  if (lane < 8) {
    int d = lane * 4;
    float4 bv = *(const float4*)(b1 + d);
    float o0 = acc0 + bv.x;
    float o1 = acc1 + bv.y;
    float o2 = acc2 + bv.z;
    float o3 = acc3 + bv.w;
    o0 = o0 > 0.f ? o0 : expm1f(o0);
    o1 = o1 > 0.f ? o1 : expm1f(o1);
    o2 = o2 > 0.f ? o2 : expm1f(o2);
    o3 = o3 > 0.f ? o3 : expm1f(o3);
    *(float4*)(hout + (size_t)n * 32 + d) = make_float4(o0, o1, o2, o3);
  }
}

// ---------------------------------------------------------------------------
// Layer-2 aggregation + log_softmax, same two-phase structure.
// Messages fp8: row 128 B -> 2B/lane (cols (lane&7)*2+{0,1}, head lane>>3).
// out[0:N*16] = log_softmax, out[N*16:] = logits.
// ---------------------------------------------------------------------------
__global__ __launch_bounds__(256) void aggregate2_k(const unsigned char* __restrict__ xq,
                                                    const float* __restrict__ asrc,
                                                    const float* __restrict__ adst,
                                                    const unsigned* __restrict__ cnt,
                                                    const unsigned* __restrict__ bucket,
                                                    const float* __restrict__ b2,
                                                    float* __restrict__ out, int N) {
  __shared__ float wlds[4][64][8];
  const int lane = threadIdx.x & 63;
  const int wv = threadIdx.x >> 6;
  const int n = blockIdx.x * 4 + wv;
  const int nn = n < N ? n : N - 1;
  int deg = (int)cnt[nn];
  deg = deg > BSTRIDE ? BSTRIDE : deg;
  const unsigned sv = bucket[((size_t)nn << 6) + lane];

  // ---- Phase A ----
  float w[8];
  if (lane < deg) {
    const float4* ap = (const float4*)(asrc + (size_t)sv * 8);
    const float4* bp = (const float4*)(adst + (size_t)nn * 8);
    float4 a0 = ap[0], a1 = ap[1];
    float4 b0 = bp[0], b1v = bp[1];
    float e[8] = {a0.x + b0.x, a0.y + b0.y, a0.z + b0.z, a0.w + b0.w,
                  a1.x + b1v.x, a1.y + b1v.y, a1.z + b1v.z, a1.w + b1v.w};
#pragma unroll
    for (int j = 0; j < 8; ++j) {
      float t = e[j];
      t = t > 0.f ? t : LEAK * t;
      w[j] = __expf(t);
    }
  } else {
#pragma unroll
    for (int j = 0; j < 8; ++j) w[j] = 0.f;
  }
#pragma unroll
  for (int j = 0; j < 8; ++j) {
    float v = w[j];
#pragma unroll
    for (int m = 1; m < 64; m <<= 1) v += __shfl_xor(v, m, 64);
    wlds[wv][lane][j] = w[j] * (0.125f / v);
  }
  __syncthreads();
  if (n >= N) return;

  // ---- Phase B ----
  const int h = lane >> 3;
  const float* wp = &wlds[wv][0][h];

  float acc0 = 0.f, acc1 = 0.f;
#pragma unroll 4
  for (int i = 0; i < deg; ++i) {
    unsigned s = __shfl(sv, i, 64);
    float w8 = wp[i * 8];
    unsigned short raw = *(const unsigned short*)(xq + (size_t)s * 128 + lane * 2);
    f32x2 v = __builtin_amdgcn_cvt_pk_f32_fp8((int)raw, false);
    acc0 += w8 * v.x;
    acc1 += w8 * v.y;
  }

#pragma unroll
  for (int m = 8; m < 64; m <<= 1) {
    acc0 += __shfl_xor(acc0, m, 64);
    acc1 += __shfl_xor(acc1, m, 64);
  }
  int c = (lane & 7) * 2;
  float l0 = acc0 + b2[c];
  float l1 = acc1 + b2[c + 1];

  float m2 = fmaxf(l0, l1);
#pragma unroll
  for (int m = 1; m < 8; m <<= 1) m2 = fmaxf(m2, __shfl_xor(m2, m, 64));
  float es = __expf(l0 - m2) + __expf(l1 - m2);
#pragma unroll
  for (int m = 1; m < 8; m <<= 1) es += __shfl_xor(es, m, 64);
  float lse = logf(es) + m2;

  if (lane < 8) {
    *(float2*)(out + (size_t)n * 16 + c) = make_float2(l0 - lse, l1 - lse);
    *(float2*)(out + (size_t)N * 16 + (size_t)n * 16 + c) = make_float2(l0, l1);
  }
}

// ---------------------------------------------------------------------------
extern "C" void kernel_launch(void* const* d_in, const int* in_sizes, int n_in,
                              void* d_out, int out_size, void* d_ws, size_t ws_size,
                              hipStream_t stream) {
  const float* x      = (const float*)d_in[0];
  const int*   ei     = (const int*)d_in[1];
  const float* W1     = (const float*)d_in[2];
  const float* a_src1 = (const float*)d_in[3];
  const float* a_dst1 = (const float*)d_in[4];
  const float* b1     = (const float*)d_in[5];
  const float* W2     = (const float*)d_in[6];
  const float* a_src2 = (const float*)d_in[7];
  const float* a_dst2 = (const float*)d_in[8];
  const float* b2     = (const float*)d_in[9];

  const int N = in_sizes[0] / 128;  // F = 128
  const int E = in_sizes[1] / 2;

  char* w = (char*)d_ws;
  size_t used = 0;
  auto alloc = [&](size_t bytes) -> void* {
    size_t aligned = (bytes + 255) & ~(size_t)255;
    void* p = w + used;
    used += aligned;
    return p;
  };
  unsigned char* xh1q = (unsigned char*)alloc((size_t)N * 256);  // fp8 L1 rows
  unsigned char* xh2q = xh1q;  // alias: gemm2 writes after agg1 consumed xh1q
  float*    hbuf   = (float*)alloc((size_t)N * 32 * 4);
  float*    asrc   = (float*)alloc((size_t)N * 8 * 4);   // reused L1 then L2
  float*    adst   = (float*)alloc((size_t)N * 8 * 4);
  unsigned* cnt    = (unsigned*)alloc((size_t)N * 4);
  unsigned* bucket = (unsigned*)alloc((size_t)N * BSTRIDE * 4);
  f16*      w1t    = (f16*)alloc((size_t)128 * 256 * 2);
  f16*      w2t    = (f16*)alloc((size_t)32 * 128 * 2);
  (void)ws_size;

  float* out = (float*)d_out;
  const int gy = (N + 63) / 64;

  // ---- prep ----
  transpose_w_k<<<(128 * 256 + 255) / 256, 256, 0, stream>>>(W1, w1t, 128, 256);
  transpose_w_k<<<(32 * 128 + 255) / 256, 256, 0, stream>>>(W2, w2t, 32, 128);
  hipMemsetAsync(cnt, 0, (size_t)N * 4, stream);

  // ---- Layer 1: MFMA GEMM + att logits + fp8 store + tail bucket-fill ----
  gemm_att_mfma_k<128, 32, true, true><<<dim3(4, gy), 256, 0, stream>>>(
      x, w1t, xh1q, a_src1, a_dst1, asrc, adst, N, 256, ei, E, N, cnt, bucket);

  // ---- Layer 1 aggregation -> h ----
  aggregate1_k<<<(N + 3) / 4, 256, 0, stream>>>(xh1q, asrc, adst, cnt, bucket, b1, hbuf, N);

  // ---- Layer 2 ----
  gemm_att_mfma_k<32, 16, true, false><<<dim3(2, gy), 256, 0, stream>>>(
      hbuf, w2t, xh2q, a_src2, a_dst2, asrc, adst, N, 128, nullptr, 0, 0, nullptr, nullptr);
  aggregate2_k<<<(N + 3) / 4, 256, 0, stream>>>(xh2q, asrc, adst, cnt, bucket, b2, out, N);
}

// Round 11
// 476.012 us; speedup vs baseline: 1.2258x; 1.0844x over previous
//
#include <hip/hip_runtime.h>
#include <hip/hip_bf16.h>
#include <hip/hip_fp16.h>
#include <math.h>

#define LEAK 0.2f
#define BSTRIDE 64  // bucket capacity per node; P(deg>64) ~ 1e-19

typedef _Float16 f16;
typedef _Float16 f16x2 __attribute__((ext_vector_type(2)));
typedef _Float16 f16x4 __attribute__((ext_vector_type(4)));
typedef _Float16 f16x8 __attribute__((ext_vector_type(8)));
typedef float f32x2 __attribute__((ext_vector_type(2)));
typedef float f32x4 __attribute__((ext_vector_type(4)));

__device__ inline unsigned char f32_to_fp8(float v) {
  int p = __builtin_amdgcn_cvt_pk_fp8_f32(v, v, 0, false);
  return (unsigned char)(p & 0xff);
}

// ---------------------------------------------------------------------------
// W[K][NC] fp32 -> Wt[NC][K] f16
// ---------------------------------------------------------------------------
__global__ void transpose_w_k(const float* __restrict__ W, f16* __restrict__ Wt,
                              int K, int NC) {
  int idx = blockIdx.x * 256 + threadIdx.x;
  if (idx >= K * NC) return;
  int n = idx / K, k = idx - n * K;
  Wt[idx] = (f16)W[(size_t)k * NC + n];
}

// ---------------------------------------------------------------------------
// MFMA GEMM + fused att logits + (optional) tail bucket-fill. (R8/R9-tuned:
// pad-free swizzled LDS, pre-transposed B, plain cnt + nontemporal scatter.)
// ---------------------------------------------------------------------------
template <int K, int DH, bool FP8OUT, bool FILL>
__global__ __launch_bounds__(256) void gemm_att_mfma_k(
    const float* __restrict__ A, const f16* __restrict__ Bt,
    void* __restrict__ Cout, const float* __restrict__ a_src,
    const float* __restrict__ a_dst, float* __restrict__ asrc,
    float* __restrict__ adst, int M, int NC,
    const int* __restrict__ ei, int E, int Nn,
    unsigned* __restrict__ cnt, unsigned* __restrict__ bucket) {
  constexpr int CH = K / 8;  // 16B chunks per row
  __shared__ f16 As[64 * K];
  __shared__ f16 Bs[64 * K];
  const int tid = threadIdx.x;
  const int row0 = blockIdx.y * 64;
  const int col0 = blockIdx.x * 64;

#pragma unroll
  for (int it = 0; it < (64 * CH) / 256; ++it) {
    int idx = it * 256 + tid;
    int r = idx / CH, c = idx - r * CH;
    int grow = row0 + r;
    float4 v0 = make_float4(0.f, 0.f, 0.f, 0.f), v1 = v0;
    if (grow < M) {
      const float* gp = A + (size_t)grow * K + c * 8;
      v0 = *(const float4*)gp;
      v1 = *(const float4*)(gp + 4);
    }
    f16x8 h = {(f16)v0.x, (f16)v0.y, (f16)v0.z, (f16)v0.w,
               (f16)v1.x, (f16)v1.y, (f16)v1.z, (f16)v1.w};
    *(f16x8*)&As[r * K + (((c + r) & (CH - 1)) << 3)] = h;
  }
#pragma unroll
  for (int it = 0; it < (64 * CH) / 256; ++it) {
    int idx = it * 256 + tid;
    int n = idx / CH, c = idx - n * CH;
    f16x8 h = *(const f16x8*)(Bt + (size_t)(col0 + n) * K + c * 8);
    *(f16x8*)&Bs[n * K + (((c + n) & (CH - 1)) << 3)] = h;
  }
  __syncthreads();

  const int wv = tid >> 6;
  const int lane = tid & 63;
  const int l16 = lane & 15;
  const int l4 = lane >> 4;

  f32x4 acc[4];
#pragma unroll
  for (int ct = 0; ct < 4; ++ct) acc[ct] = (f32x4){0.f, 0.f, 0.f, 0.f};

  const int ar = wv * 16 + l16;
#pragma unroll
  for (int kt = 0; kt < K / 32; ++kt) {
    int aj = kt * 4 + l4;
    f16x8 av = *(const f16x8*)&As[ar * K + (((aj + ar) & (CH - 1)) << 3)];
#pragma unroll
    for (int ct = 0; ct < 4; ++ct) {
      int br = ct * 16 + l16;
      f16x8 bv = *(const f16x8*)&Bs[br * K + (((aj + br) & (CH - 1)) << 3)];
      acc[ct] = __builtin_amdgcn_mfma_f32_16x16x32_f16(av, bv, acc[ct], 0, 0, 0);
    }
  }

  constexpr int HPB = 64 / DH;
  constexpr int CTH = DH / 16;
  float ps[HPB][4], pd[HPB][4];
#pragma unroll
  for (int hl = 0; hl < HPB; ++hl)
#pragma unroll
    for (int r = 0; r < 4; ++r) { ps[hl][r] = 0.f; pd[hl][r] = 0.f; }

#pragma unroll
  for (int ct = 0; ct < 4; ++ct) {
    int col = col0 + ct * 16 + l16;
    float vs = a_src[col];
    float vd = a_dst[col];
    int hl = ct / CTH;
#pragma unroll
    for (int r = 0; r < 4; ++r) {
      ps[hl][r] += acc[ct][r] * vs;
      pd[hl][r] += acc[ct][r] * vd;
      int grow = row0 + wv * 16 + l4 * 4 + r;
      if (grow < M) {
        if (FP8OUT) {
          ((unsigned char*)Cout)[(size_t)grow * NC + col] = f32_to_fp8(acc[ct][r]);
        } else {
          ((f16*)Cout)[(size_t)grow * NC + col] = (f16)acc[ct][r];
        }
      }
    }
  }

#pragma unroll
  for (int hl = 0; hl < HPB; ++hl) {
#pragma unroll
    for (int r = 0; r < 4; ++r) {
      float s = ps[hl][r], d = pd[hl][r];
#pragma unroll
      for (int m = 1; m < 16; m <<= 1) {
        s += __shfl_xor(s, m, 64);
        d += __shfl_xor(d, m, 64);
      }
      if (l16 == 0) {
        int grow = row0 + wv * 16 + l4 * 4 + r;
        int h = (col0 / DH) + hl;
        if (grow < M) {
          asrc[(size_t)grow * 8 + h] = s;
          adst[(size_t)grow * 8 + h] = d;
        }
      }
    }
  }

  if (FILL) {
    const int nthreads = (int)(gridDim.x * gridDim.y) * 256;
    const int Mtot = E + Nn;
    for (int p = (int)(blockIdx.y * gridDim.x + blockIdx.x) * 256 + tid;
         p < Mtot; p += nthreads) {
      int s, d;
      if (p < E) {
        s = ei[p];
        d = ei[E + p];
      } else {
        s = d = p - E;
      }
      unsigned pos = atomicAdd(&cnt[d], 1u);
      if (pos < BSTRIDE)
        __builtin_nontemporal_store((unsigned)s, &bucket[((size_t)d << 6) + pos]);
    }
  }
}

// ---------------------------------------------------------------------------
// Layer-1 aggregation, two-phase, DUAL-EDGE phase B:
//  Phase A (lane = edge): weights for all edges in parallel, butterfly
//    normalize (0.125 folded), fp32 -> LDS [wave][edge][head].
//  Phase B: lanes 0-31 = edge i, lanes 32-63 = edge i+1; 8 B/lane covers the
//    256-B fp8 row; loop trips halve vs single-edge. Merge = shfl_xor 32.
//  sv zeroed for lane >= deg so the odd-tail phantom edge reads row 0 w/ w=0.
// ---------------------------------------------------------------------------
__global__ __launch_bounds__(256) void aggregate1_k(const unsigned char* __restrict__ xh8,
                                                    const float* __restrict__ asrc,
                                                    const float* __restrict__ adst,
                                                    const unsigned* __restrict__ cnt,
                                                    const unsigned* __restrict__ bucket,
                                                    const float* __restrict__ b1,
                                                    float* __restrict__ hout, int N) {
  __shared__ float wlds[4][64][8];
  const int lane = threadIdx.x & 63;
  const int wv = threadIdx.x >> 6;
  const int n = blockIdx.x * 4 + wv;
  const int nn = n < N ? n : N - 1;  // clamp so no wave skips the barrier
  int deg = (int)cnt[nn];
  deg = deg > BSTRIDE ? BSTRIDE : deg;
  unsigned sv = bucket[((size_t)nn << 6) + lane];
  if (lane >= deg) sv = 0;  // phantom edges -> row 0, weight 0

  // ---- Phase A: per-edge weights ----
  float w[8];
  if (lane < deg) {
    const float4* ap = (const float4*)(asrc + (size_t)sv * 8);
    const float4* bp = (const float4*)(adst + (size_t)nn * 8);
    float4 a0 = ap[0], a1 = ap[1];
    float4 b0 = bp[0], b1v = bp[1];
    float e[8] = {a0.x + b0.x, a0.y + b0.y, a0.z + b0.z, a0.w + b0.w,
                  a1.x + b1v.x, a1.y + b1v.y, a1.z + b1v.z, a1.w + b1v.w};
#pragma unroll
    for (int j = 0; j < 8; ++j) {
      float t = e[j];
      t = t > 0.f ? t : LEAK * t;
      w[j] = __expf(t);
    }
  } else {
#pragma unroll
    for (int j = 0; j < 8; ++j) w[j] = 0.f;
  }
#pragma unroll
  for (int j = 0; j < 8; ++j) {
    float v = w[j];
#pragma unroll
    for (int m = 1; m < 64; m <<= 1) v += __shfl_xor(v, m, 64);
    wlds[wv][lane][j] = w[j] * (0.125f / v);
  }
  __syncthreads();
  if (n >= N) return;

  // ---- Phase B: dual-edge weighted row accumulate ----
  const int sub = lane >> 5;       // 0: edge i, 1: edge i+1
  const int sl = lane & 31;        // covers bytes sl*8..+8 of the 256-B row
  const int h = sl >> 2;           // head (8 heads x 4 lanes x 8 B)
  const uint2* xw = (const uint2*)xh8;  // row = 32 uint2
  const float* wbase = &wlds[wv][0][h];

  float a0 = 0.f, a1 = 0.f, a2 = 0.f, a3 = 0.f;
  float a4 = 0.f, a5 = 0.f, a6 = 0.f, a7 = 0.f;
#pragma unroll 4
  for (int i = 0; i < deg; i += 2) {
    unsigned s0 = __shfl(sv, i, 64);       // readlane (uniform)
    unsigned s1 = __shfl(sv, i + 1, 64);   // readlane (uniform)
    unsigned s = sub ? s1 : s0;
    float w8 = wbase[(i + sub) * 8];       // LDS broadcast, conflict-free
    uint2 b = xw[(size_t)s * 32 + sl];
    f32x2 p0 = __builtin_amdgcn_cvt_pk_f32_fp8(b.x, false);
    f32x2 p1 = __builtin_amdgcn_cvt_pk_f32_fp8(b.x, true);
    f32x2 p2 = __builtin_amdgcn_cvt_pk_f32_fp8(b.y, false);
    f32x2 p3 = __builtin_amdgcn_cvt_pk_f32_fp8(b.y, true);
    a0 += w8 * p0.x; a1 += w8 * p0.y; a2 += w8 * p1.x; a3 += w8 * p1.y;
    a4 += w8 * p2.x; a5 += w8 * p2.y; a6 += w8 * p3.x; a7 += w8 * p3.y;
  }

  // merge the two edge halves, then sum over heads (xor 4,8,16)
#pragma unroll
  for (int m = 32; m >= 4; m >>= 1) {
    if (m == 32 || m <= 16) {
      a0 += __shfl_xor(a0, m, 64); a1 += __shfl_xor(a1, m, 64);
      a2 += __shfl_xor(a2, m, 64); a3 += __shfl_xor(a3, m, 64);
      a4 += __shfl_xor(a4, m, 64); a5 += __shfl_xor(a5, m, 64);
      a6 += __shfl_xor(a6, m, 64); a7 += __shfl_xor(a7, m, 64);
    }
  }
  if (lane < 4) {
    int d = lane * 8;  // lane sl covers dims sl*8..+8
    float4 bv0 = *(const float4*)(b1 + d);
    float4 bv1 = *(const float4*)(b1 + d + 4);
    float o0 = a0 + bv0.x, o1 = a1 + bv0.y, o2 = a2 + bv0.z, o3 = a3 + bv0.w;
    float o4 = a4 + bv1.x, o5 = a5 + bv1.y, o6 = a6 + bv1.z, o7 = a7 + bv1.w;
    o0 = o0 > 0.f ? o0 : expm1f(o0);
    o1 = o1 > 0.f ? o1 : expm1f(o1);
    o2 = o2 > 0.f ? o2 : expm1f(o2);
    o3 = o3 > 0.f ? o3 : expm1f(o3);
    o4 = o4 > 0.f ? o4 : expm1f(o4);
    o5 = o5 > 0.f ? o5 : expm1f(o5);
    o6 = o6 > 0.f ? o6 : expm1f(o6);
    o7 = o7 > 0.f ? o7 : expm1f(o7);
    *(float4*)(hout + (size_t)n * 32 + d) = make_float4(o0, o1, o2, o3);
    *(float4*)(hout + (size_t)n * 32 + d + 4) = make_float4(o4, o5, o6, o7);
  }
}

// ---------------------------------------------------------------------------
// Layer-2 aggregation + log_softmax, dual-edge phase B: 4 B/lane covers the
// 128-B fp8 row; lanes 0-31 edge i, 32-63 edge i+1.
// out[0:N*16] = log_softmax, out[N*16:] = logits.
// ---------------------------------------------------------------------------
__global__ __launch_bounds__(256) void aggregate2_k(const unsigned char* __restrict__ xq,
                                                    const float* __restrict__ asrc,
                                                    const float* __restrict__ adst,
                                                    const unsigned* __restrict__ cnt,
                                                    const unsigned* __restrict__ bucket,
                                                    const float* __restrict__ b2,
                                                    float* __restrict__ out, int N) {
  __shared__ float wlds[4][64][8];
  const int lane = threadIdx.x & 63;
  const int wv = threadIdx.x >> 6;
  const int n = blockIdx.x * 4 + wv;
  const int nn = n < N ? n : N - 1;
  int deg = (int)cnt[nn];
  deg = deg > BSTRIDE ? BSTRIDE : deg;
  unsigned sv = bucket[((size_t)nn << 6) + lane];
  if (lane >= deg) sv = 0;

  // ---- Phase A ----
  float w[8];
  if (lane < deg) {
    const float4* ap = (const float4*)(asrc + (size_t)sv * 8);
    const float4* bp = (const float4*)(adst + (size_t)nn * 8);
    float4 a0 = ap[0], a1 = ap[1];
    float4 b0 = bp[0], b1v = bp[1];
    float e[8] = {a0.x + b0.x, a0.y + b0.y, a0.z + b0.z, a0.w + b0.w,
                  a1.x + b1v.x, a1.y + b1v.y, a1.z + b1v.z, a1.w + b1v.w};
#pragma unroll
    for (int j = 0; j < 8; ++j) {
      float t = e[j];
      t = t > 0.f ? t : LEAK * t;
      w[j] = __expf(t);
    }
  } else {
#pragma unroll
    for (int j = 0; j < 8; ++j) w[j] = 0.f;
  }
#pragma unroll
  for (int j = 0; j < 8; ++j) {
    float v = w[j];
#pragma unroll
    for (int m = 1; m < 64; m <<= 1) v += __shfl_xor(v, m, 64);
    wlds[wv][lane][j] = w[j] * (0.125f / v);
  }
  __syncthreads();
  if (n >= N) return;

  // ---- Phase B: dual-edge ----
  const int sub = lane >> 5;
  const int sl = lane & 31;      // covers bytes sl*4..+4 of the 128-B row
  const int h = sl >> 2;         // head (8 heads x 4 lanes x 4 B)
  const unsigned* xw = (const unsigned*)xq;  // row = 32 words
  const float* wbase = &wlds[wv][0][h];

  float a0 = 0.f, a1 = 0.f, a2 = 0.f, a3 = 0.f;
#pragma unroll 4
  for (int i = 0; i < deg; i += 2) {
    unsigned s0 = __shfl(sv, i, 64);
    unsigned s1 = __shfl(sv, i + 1, 64);
    unsigned s = sub ? s1 : s0;
    float w8 = wbase[(i + sub) * 8];
    unsigned b = xw[(size_t)s * 32 + sl];
    f32x2 p0 = __builtin_amdgcn_cvt_pk_f32_fp8(b, false);
    f32x2 p1 = __builtin_amdgcn_cvt_pk_f32_fp8(b, true);
    a0 += w8 * p0.x; a1 += w8 * p0.y; a2 += w8 * p1.x; a3 += w8 * p1.y;
  }

  // merge halves + head sum
#pragma unroll
  for (int m = 32; m >= 4; m >>= 1) {
    if (m == 32 || m <= 16) {
      a0 += __shfl_xor(a0, m, 64); a1 += __shfl_xor(a1, m, 64);
      a2 += __shfl_xor(a2, m, 64); a3 += __shfl_xor(a3, m, 64);
    }
  }
  // lanes 0-3 hold cols lane*4..+4
  int c = (lane & 3) * 4;
  float4 bv = *(const float4*)(b2 + c);
  float l0 = a0 + bv.x, l1 = a1 + bv.y, l2 = a2 + bv.z, l3 = a3 + bv.w;

  float mx = fmaxf(fmaxf(l0, l1), fmaxf(l2, l3));
  mx = fmaxf(mx, __shfl_xor(mx, 1, 64));
  mx = fmaxf(mx, __shfl_xor(mx, 2, 64));
  float es = __expf(l0 - mx) + __expf(l1 - mx) + __expf(l2 - mx) + __expf(l3 - mx);
  es += __shfl_xor(es, 1, 64);
  es += __shfl_xor(es, 2, 64);
  float lse = logf(es) + mx;

  if (lane < 4) {
    *(float4*)(out + (size_t)n * 16 + c) = make_float4(l0 - lse, l1 - lse, l2 - lse, l3 - lse);
    *(float4*)(out + (size_t)N * 16 + (size_t)n * 16 + c) = make_float4(l0, l1, l2, l3);
  }
}

// ---------------------------------------------------------------------------
extern "C" void kernel_launch(void* const* d_in, const int* in_sizes, int n_in,
                              void* d_out, int out_size, void* d_ws, size_t ws_size,
                              hipStream_t stream) {
  const float* x      = (const float*)d_in[0];
  const int*   ei     = (const int*)d_in[1];
  const float* W1     = (const float*)d_in[2];
  const float* a_src1 = (const float*)d_in[3];
  const float* a_dst1 = (const float*)d_in[4];
  const float* b1     = (const float*)d_in[5];
  const float* W2     = (const float*)d_in[6];
  const float* a_src2 = (const float*)d_in[7];
  const float* a_dst2 = (const float*)d_in[8];
  const float* b2     = (const float*)d_in[9];

  const int N = in_sizes[0] / 128;  // F = 128
  const int E = in_sizes[1] / 2;

  char* w = (char*)d_ws;
  size_t used = 0;
  auto alloc = [&](size_t bytes) -> void* {
    size_t aligned = (bytes + 255) & ~(size_t)255;
    void* p = w + used;
    used += aligned;
    return p;
  };
  unsigned char* xh1q = (unsigned char*)alloc((size_t)N * 256);  // fp8 L1 rows
  unsigned char* xh2q = xh1q;  // alias: gemm2 writes after agg1 consumed xh1q
  float*    hbuf   = (float*)alloc((size_t)N * 32 * 4);
  float*    asrc   = (float*)alloc((size_t)N * 8 * 4);   // reused L1 then L2
  float*    adst   = (float*)alloc((size_t)N * 8 * 4);
  unsigned* cnt    = (unsigned*)alloc((size_t)N * 4);
  unsigned* bucket = (unsigned*)alloc((size_t)N * BSTRIDE * 4);
  f16*      w1t    = (f16*)alloc((size_t)128 * 256 * 2);
  f16*      w2t    = (f16*)alloc((size_t)32 * 128 * 2);
  (void)ws_size;

  float* out = (float*)d_out;
  const int gy = (N + 63) / 64;

  // ---- prep ----
  transpose_w_k<<<(128 * 256 + 255) / 256, 256, 0, stream>>>(W1, w1t, 128, 256);
  transpose_w_k<<<(32 * 128 + 255) / 256, 256, 0, stream>>>(W2, w2t, 32, 128);
  hipMemsetAsync(cnt, 0, (size_t)N * 4, stream);

  // ---- Layer 1: MFMA GEMM + att logits + fp8 store + tail bucket-fill ----
  gemm_att_mfma_k<128, 32, true, true><<<dim3(4, gy), 256, 0, stream>>>(
      x, w1t, xh1q, a_src1, a_dst1, asrc, adst, N, 256, ei, E, N, cnt, bucket);

  // ---- Layer 1 aggregation -> h ----
  aggregate1_k<<<(N + 3) / 4, 256, 0, stream>>>(xh1q, asrc, adst, cnt, bucket, b1, hbuf, N);

  // ---- Layer 2 ----
  gemm_att_mfma_k<32, 16, true, false><<<dim3(2, gy), 256, 0, stream>>>(
      hbuf, w2t, xh2q, a_src2, a_dst2, asrc, adst, N, 128, nullptr, 0, 0, nullptr, nullptr);
  aggregate2_k<<<(N + 3) / 4, 256, 0, stream>>>(xh2q, asrc, adst, cnt, bucket, b2, out, N);
}